// Round 2
// baseline (785.128 us; speedup 1.0000x reference)
//
#include <hip/hip_runtime.h>
#include <hip/hip_cooperative_groups.h>
#include <cstddef>

namespace cg = cooperative_groups;

// Problem constants (all powers of two).
#define B_    128
#define IN_   256
#define OUT_  256
#define HS_   512

#define NTHR_ 512

__device__ __forceinline__ float clip1(float x) {
    return fminf(fmaxf(x, -1.f), 1.f);
}

// ---------------------------------------------------------------------------
// Cooperative fused kernel, templated on grid size.
//  NBLK=512: 2 blocks/CU, 2 rounds x 64 samples  (preferred)
//  NBLK=256: 1 block/CU, 4 rounds x 32 samples   (fallback geometry)
// Per block: 64 hebb rows (8 waves x 8 rows), hebb row fragments staged in
// registers between phase 1 (hactiv) and phase 3 (hebb update), so hebb is
// fetched from HBM exactly once.
// Phase 1 issues ALL 16 hebb float4 loads per wave before any compute
// (the staging regs are the load destinations) -> 16 KB in flight per wave,
// enough outstanding requests to reach HBM BW instead of latency-binding.
// ---------------------------------------------------------------------------
template<int NBLK>
__global__ __launch_bounds__(NTHR_, 4) void fused_plastic(
    const float* __restrict__ inputs,   // [B, IN]
    const float* __restrict__ hidden,   // [B, HS]
    const float* __restrict__ hebb,     // [B, HS, HS]
    const float* __restrict__ i2h_w,    // [HS, IN]
    const float* __restrict__ i2h_b,    // [HS]
    const float* __restrict__ w,        // [HS, HS]
    const float* __restrict__ alpha,    // [HS, HS]
    const float* __restrict__ h2o_w,    // [OUT, HS]
    const float* __restrict__ h2o_b,    // [OUT]
    const float* __restrict__ h2v_w,    // [HS]
    const float* __restrict__ h2v_b,    // [1]
    const float* __restrict__ h2da_w,   // [HS]
    const float* __restrict__ h2da_b,   // [1]
    float* __restrict__ activout,       // [B, OUT]
    float* __restrict__ valueout,       // [B]
    float* __restrict__ hactiv,         // [B, HS]
    float* __restrict__ hebb_new,       // [B, HS, HS]
    float* __restrict__ ws_pd,          // [B*8] per-(sample,block) da partials
    float* __restrict__ ws_pv)          // [B*8] per-(sample,block) value partials
{
    cg::grid_group grid = cg::this_grid();

    constexpr int ROUNDS = 1024 / NBLK;   // 2 (512 blk) or 4 (256 blk)
    constexpr int SPX    = NBLK / 64;     // samples per XCD per round
    constexpr int SPR    = NBLK / 8;      // samples per round

    const int blk  = blockIdx.x;
    const int xcd  = blk & 7;             // heuristic XCD id (perf-only)
    const int slot = blk >> 3;
    const int sub  = slot >> 3;           // sample-within-xcd (0..SPX-1)
    const int bs   = slot & 7;            // block-within-sample (0..7)
    const int tid  = threadIdx.x;
    const int wave = tid >> 6;            // 0..7
    const int lane = tid & 63;

    __shared__ float s_pd[8];
    __shared__ float s_pv[8];
    __shared__ float s_h[HS_];
    __shared__ float s_part[512];

    const int i_base = bs * 64 + wave * 8;

    for (int r = 0; r < ROUNDS; ++r) {
        const int b = r * SPR + xcd * SPX + sub;

        // Lane-fixed per-sample operands.
        const float4* hid4 = (const float4*)(hidden + (size_t)b * HS_);
        const float4 h0  = hid4[lane];
        const float4 h1  = hid4[lane + 64];
        const float4 in4 = ((const float4*)(inputs + (size_t)b * IN_))[lane];

        // ---- phase 1a: issue ALL hebb loads (staging regs = destinations) --
        float4 hbA[8], hbB[8];
        const float* hrow0 = hebb + ((size_t)b * HS_ + i_base) * HS_;
        #pragma unroll
        for (int q = 0; q < 8; ++q) {
            const float4* hbp = (const float4*)(hrow0 + (size_t)q * HS_);
            hbA[q] = hbp[lane];
            hbB[q] = hbp[lane + 64];
        }

        // ---- phase 1b: hactiv rows (w/alpha/i2h loads are L2-resident) ----
        float h_row[8];
        float pd = 0.f, pv = 0.f;
        #pragma unroll
        for (int q = 0; q < 8; ++q) {
            const int i = i_base + q;
            const float4* wr = (const float4*)(w     + (size_t)i * HS_);
            const float4* ar = (const float4*)(alpha + (size_t)i * HS_);
            const float4 wv0 = wr[lane], wv1 = wr[lane + 64];
            const float4 av0 = ar[lane], av1 = ar[lane + 64];
            const float4 iw  = ((const float4*)(i2h_w + (size_t)i * IN_))[lane];

            float acc;
            acc  = (wv0.x + av0.x * hbA[q].x) * h0.x;
            acc += (wv0.y + av0.y * hbA[q].y) * h0.y;
            acc += (wv0.z + av0.z * hbA[q].z) * h0.z;
            acc += (wv0.w + av0.w * hbA[q].w) * h0.w;
            acc += (wv1.x + av1.x * hbB[q].x) * h1.x;
            acc += (wv1.y + av1.y * hbB[q].y) * h1.y;
            acc += (wv1.z + av1.z * hbB[q].z) * h1.z;
            acc += (wv1.w + av1.w * hbB[q].w) * h1.w;
            acc += iw.x * in4.x + iw.y * in4.y + iw.z * in4.z + iw.w * in4.w;

            // 64-lane butterfly all-reduce: every lane gets the row sum.
            #pragma unroll
            for (int off = 1; off < 64; off <<= 1)
                acc += __shfl_xor(acc, off, 64);

            const float h = tanhf(acc + i2h_b[i]);
            h_row[q] = h;
            if (lane == 0) {
                pd += h * h2da_w[i];
                pv += h * h2v_w[i];
            }
        }

        // vectorized hactiv store (rows i_base..i_base+7 are consecutive)
        if (lane == 0) {
            float4 ha0 = make_float4(h_row[0], h_row[1], h_row[2], h_row[3]);
            float4 ha1 = make_float4(h_row[4], h_row[5], h_row[6], h_row[7]);
            float4* hp = (float4*)(hactiv + (size_t)b * HS_ + i_base);
            hp[0] = ha0;
            hp[1] = ha1;
            s_pd[wave] = pd;
            s_pv[wave] = pv;
        }
        __syncthreads();
        if (tid == 0) {
            float sd = 0.f, sv = 0.f;
            #pragma unroll
            for (int k = 0; k < 8; ++k) { sd += s_pd[k]; sv += s_pv[k]; }
            ws_pd[b * 8 + bs] = sd;
            ws_pv[b * 8 + bs] = sv;
        }
        __threadfence();
        grid.sync();

        // ---- phase 3: finalize da, update hebb from staged registers ----
        float sd = 0.f, sv = 0.f;
        #pragma unroll
        for (int k = 0; k < 8; ++k) {
            sd += ws_pd[b * 8 + k];
            sv += ws_pv[b * 8 + k];
        }
        const float da_b = tanhf(sd + h2da_b[0]);
        if (bs == 0 && tid == 0)
            valueout[b] = sv + h2v_b[0];

        #pragma unroll
        for (int q = 0; q < 8; ++q) {
            const int i = i_base + q;
            const float sc = da_b * h_row[q];
            float4 o0, o1;
            o0.x = clip1(fmaf(sc, h0.x, hbA[q].x));
            o0.y = clip1(fmaf(sc, h0.y, hbA[q].y));
            o0.z = clip1(fmaf(sc, h0.z, hbA[q].z));
            o0.w = clip1(fmaf(sc, h0.w, hbA[q].w));
            o1.x = clip1(fmaf(sc, h1.x, hbB[q].x));
            o1.y = clip1(fmaf(sc, h1.y, hbB[q].y));
            o1.z = clip1(fmaf(sc, h1.z, hbB[q].z));
            o1.w = clip1(fmaf(sc, h1.w, hbB[q].w));
            float4* op = (float4*)(hebb_new + ((size_t)b * HS_ + i) * HS_);
            op[lane]      = o0;
            op[lane + 64] = o1;
        }
    }

    // ---- heads tail: activout (all hactiv visible since last grid.sync) ---
    constexpr int BPS = NBLK / B_;        // blocks per sample (4 or 2)
    constexpr int OPB = OUT_ / BPS;       // outputs per block (64 or 128)
    constexpr int SEG = NTHR_ / OPB;      // dot-segments (8 or 4)
    constexpr int F4S = (HS_ / 4) / SEG;  // float4 per segment (16 or 32)

    const int ba   = blk / BPS;           // sample
    const int part = blk % BPS;           // output-quarter/half

    if (tid < 128)
        ((float4*)s_h)[tid] = ((const float4*)(hactiv + (size_t)ba * HS_))[tid];
    __syncthreads();

    {
        const int ol = tid % OPB;
        const int sg = tid / OPB;
        const int o  = part * OPB + ol;
        const float4* wp  = (const float4*)(h2o_w + (size_t)o * HS_);
        const float4* hp4 = (const float4*)s_h;
        float acc = 0.f;
        #pragma unroll
        for (int c = 0; c < F4S; ++c) {
            const float4 wv = wp[sg * F4S + c];
            const float4 hv = hp4[sg * F4S + c];
            acc += wv.x * hv.x + wv.y * hv.y + wv.z * hv.z + wv.w * hv.w;
        }
        s_part[sg * OPB + ol] = acc;
    }
    __syncthreads();
    if (tid < OPB) {
        const int o = part * OPB + tid;
        float acc = h2o_b[o];
        #pragma unroll
        for (int k = 0; k < SEG; ++k)
            acc += s_part[k * OPB + tid];
        activout[(size_t)ba * OUT_ + o] = acc;
    }
}

// ---------------------------------------------------------------------------
// Fallback path (original verified 3-kernel version) — used only if the
// workspace is too small for the cooperative path's 8 KB of partials.
// ---------------------------------------------------------------------------
__global__ __launch_bounds__(256) void k1_hactiv(
    const float* __restrict__ inputs, const float* __restrict__ hidden,
    const float* __restrict__ hebb, const float* __restrict__ i2h_w,
    const float* __restrict__ i2h_b, const float* __restrict__ w,
    const float* __restrict__ alpha, float* __restrict__ hactiv)
{
    const int b     = blockIdx.x & (B_ - 1);
    const int chunk = blockIdx.x >> 7;
    const int tid   = threadIdx.x;
    const int wave  = tid >> 6;
    const int lane  = tid & 63;

    const float4* hid4 = (const float4*)(hidden + (size_t)b * HS_);
    const float4  h0   = hid4[lane];
    const float4  h1   = hid4[lane + 64];
    const float4  in4  = ((const float4*)(inputs + (size_t)b * IN_))[lane];

    const int i0 = chunk * 64 + wave * 16;

    for (int r = 0; r < 16; ++r) {
        const int i = i0 + r;
        const float4* hb = (const float4*)(hebb + ((size_t)b * HS_ + i) * HS_);
        const float4* wr = (const float4*)(w     + (size_t)i * HS_);
        const float4* ar = (const float4*)(alpha + (size_t)i * HS_);

        const float4 hb0 = hb[lane];
        const float4 hb1 = hb[lane + 64];
        const float4 wv0 = wr[lane];
        const float4 wv1 = wr[lane + 64];
        const float4 av0 = ar[lane];
        const float4 av1 = ar[lane + 64];
        const float4 iw  = ((const float4*)(i2h_w + (size_t)i * IN_))[lane];

        float acc;
        acc  = (wv0.x + av0.x * hb0.x) * h0.x;
        acc += (wv0.y + av0.y * hb0.y) * h0.y;
        acc += (wv0.z + av0.z * hb0.z) * h0.z;
        acc += (wv0.w + av0.w * hb0.w) * h0.w;
        acc += (wv1.x + av1.x * hb1.x) * h1.x;
        acc += (wv1.y + av1.y * hb1.y) * h1.y;
        acc += (wv1.z + av1.z * hb1.z) * h1.z;
        acc += (wv1.w + av1.w * hb1.w) * h1.w;
        acc += iw.x * in4.x + iw.y * in4.y + iw.z * in4.z + iw.w * in4.w;

        #pragma unroll
        for (int off = 32; off > 0; off >>= 1)
            acc += __shfl_down(acc, off, 64);

        if (lane == 0)
            hactiv[(size_t)b * HS_ + i] = tanhf(acc + i2h_b[i]);
    }
}

__global__ __launch_bounds__(256) void k2_heads(
    const float* __restrict__ hactiv, const float* __restrict__ h2o_w,
    const float* __restrict__ h2o_b, const float* __restrict__ h2v_w,
    const float* __restrict__ h2v_b, const float* __restrict__ h2da_w,
    const float* __restrict__ h2da_b, float* __restrict__ activout,
    float* __restrict__ valueout, float* __restrict__ da)
{
    const int b   = blockIdx.x;
    const int tid = threadIdx.x;

    __shared__ float s_h[HS_];
    __shared__ float red_v[256];
    __shared__ float red_d[256];

    for (int t = tid; t < HS_; t += 256)
        s_h[t] = hactiv[(size_t)b * HS_ + t];
    __syncthreads();

    const float4* wr  = (const float4*)(h2o_w + (size_t)tid * HS_);
    const float4* sh4 = (const float4*)s_h;
    float acc = 0.f;
    #pragma unroll 4
    for (int q = 0; q < HS_ / 4; ++q) {
        const float4 wv = wr[q];
        const float4 hv = sh4[q];
        acc += wv.x * hv.x + wv.y * hv.y + wv.z * hv.z + wv.w * hv.w;
    }
    activout[(size_t)b * OUT_ + tid] = acc + h2o_b[tid];

    float pv = 0.f, pd = 0.f;
    for (int t = tid; t < HS_; t += 256) {
        const float hv = s_h[t];
        pv += hv * h2v_w[t];
        pd += hv * h2da_w[t];
    }
    red_v[tid] = pv;
    red_d[tid] = pd;
    __syncthreads();
    for (int s = 128; s > 0; s >>= 1) {
        if (tid < s) {
            red_v[tid] += red_v[tid + s];
            red_d[tid] += red_d[tid + s];
        }
        __syncthreads();
    }
    if (tid == 0) {
        valueout[b] = red_v[0] + h2v_b[0];
        da[b]       = tanhf(red_d[0] + h2da_b[0]);
    }
}

__global__ __launch_bounds__(256) void k3_hebb(
    const float* __restrict__ hebb, const float* __restrict__ hidden,
    const float* __restrict__ hactiv, const float* __restrict__ da,
    float* __restrict__ hebb_new)
{
    const int tid = threadIdx.x;
    const size_t base = (size_t)blockIdx.x * 1024;

    #pragma unroll
    for (int k = 0; k < 4; ++k) {
        const size_t idx = base + (size_t)k * 256 + tid;
        const int j4  = (int)(idx & 127);
        const int row = (int)(idx >> 7);
        const int i   = row & (HS_ - 1);
        const int b   = row >> 9;

        const float scale = da[b] * hactiv[(size_t)b * HS_ + i];
        const float4 hv = ((const float4*)hebb)[idx];
        const float4 hd = ((const float4*)hidden)[(size_t)b * (HS_ / 4) + j4];

        float4 r;
        r.x = fminf(fmaxf(fmaf(scale, hd.x, hv.x), -1.f), 1.f);
        r.y = fminf(fmaxf(fmaf(scale, hd.y, hv.y), -1.f), 1.f);
        r.z = fminf(fmaxf(fmaf(scale, hd.z, hv.z), -1.f), 1.f);
        r.w = fminf(fmaxf(fmaf(scale, hd.w, hv.w), -1.f), 1.f);
        ((float4*)hebb_new)[idx] = r;
    }
}

// ---------------------------------------------------------------------------
extern "C" void kernel_launch(void* const* d_in, const int* in_sizes, int n_in,
                              void* d_out, int out_size, void* d_ws, size_t ws_size,
                              hipStream_t stream)
{
    const float* inputs = (const float*)d_in[0];
    const float* hidden = (const float*)d_in[1];
    const float* hebb   = (const float*)d_in[2];
    const float* i2h_w  = (const float*)d_in[3];
    const float* i2h_b  = (const float*)d_in[4];
    const float* w      = (const float*)d_in[5];
    const float* alpha  = (const float*)d_in[6];
    const float* h2o_w  = (const float*)d_in[7];
    const float* h2o_b  = (const float*)d_in[8];
    const float* h2v_w  = (const float*)d_in[9];
    const float* h2v_b  = (const float*)d_in[10];
    const float* h2da_w = (const float*)d_in[11];
    const float* h2da_b = (const float*)d_in[12];

    float* out = (float*)d_out;
    // Output layout (flat, return order): activout | valueout | hactiv | hebb_new
    float* activout = out;                              // 128*256   = 32768
    float* valueout = out + 32768;                      // 128
    float* hactiv   = out + 32768 + 128;                // 128*512   = 65536
    float* hebb_new = out + 32768 + 128 + 65536;        // 128*512*512

    if (ws_size >= (size_t)(2 * B_ * 8 * sizeof(float))) {
        float* ws_pd = (float*)d_ws;                    // [128*8]
        float* ws_pv = ws_pd + B_ * 8;                  // [128*8]

        void* args[] = {
            (void*)&inputs, (void*)&hidden, (void*)&hebb, (void*)&i2h_w,
            (void*)&i2h_b,  (void*)&w,      (void*)&alpha, (void*)&h2o_w,
            (void*)&h2o_b,  (void*)&h2v_w,  (void*)&h2v_b, (void*)&h2da_w,
            (void*)&h2da_b, (void*)&activout, (void*)&valueout,
            (void*)&hactiv, (void*)&hebb_new, (void*)&ws_pd, (void*)&ws_pv
        };

        // Prefer 2 blocks/CU (512 blocks); verified via occupancy query so the
        // cooperative launch can never exceed co-residency.
        int maxb = 0;
        hipError_t oe = hipOccupancyMaxActiveBlocksPerMultiprocessor(
            &maxb, fused_plastic<512>, NTHR_, 0);
        if (oe == hipSuccess && maxb >= 2) {
            hipLaunchCooperativeKernel((const void*)fused_plastic<512>,
                                       dim3(512), dim3(NTHR_), args, 0, stream);
        } else {
            hipLaunchCooperativeKernel((const void*)fused_plastic<256>,
                                       dim3(256), dim3(NTHR_), args, 0, stream);
        }
    } else {
        float* da = (float*)d_ws;                       // [128] scratch
        k1_hactiv<<<dim3(1024), dim3(256), 0, stream>>>(
            inputs, hidden, hebb, i2h_w, i2h_b, w, alpha, hactiv);
        k2_heads<<<dim3(B_), dim3(256), 0, stream>>>(
            hactiv, h2o_w, h2o_b, h2v_w, h2v_b, h2da_w, h2da_b,
            activout, valueout, da);
        k3_hebb<<<dim3(8192), dim3(256), 0, stream>>>(
            hebb, hidden, hactiv, da, hebb_new);
    }
}

// Round 3
// 595.154 us; speedup vs baseline: 1.3192x; 1.3192x over previous
//
#include <hip/hip_runtime.h>
#include <hip/hip_cooperative_groups.h>
#include <cstddef>

namespace cg = cooperative_groups;

// Problem constants (all powers of two).
#define B_    128
#define IN_   256
#define OUT_  256
#define HS_   512

#define NTHR_ 512

__device__ __forceinline__ float clip1(float x) {
    return fminf(fmaxf(x, -1.f), 1.f);
}

// ---------------------------------------------------------------------------
// Cooperative fused kernel, templated on grid size.
//  NBLK=512: 2 blocks/CU, 2 rounds x 64 samples  (preferred)
//  NBLK=256: 1 block/CU, 4 rounds x 32 samples   (fallback geometry)
//
// Register budget is the whole game (round-2 spill post-mortem):
//  - launch_bounds(512, 2) -> 128-VGPR cap (empirically verified round 1).
//  - hbA (first half of each hebb row fragment) lives in registers (32 VGPR).
//  - hbB (second half) is parked in LDS: each thread writes/reads ONLY its
//    own slots, so LDS acts as a private spill store -- no barriers needed,
//    no cross-lane sharing. 64 KB/block, 69.7 KB total <= 80 KB (2 blk/CU).
//  - Phase 1a issues all 16 global loads back-to-back (16 KB/wave in flight)
//    before anything consumes them -> memory-level parallelism.
// ---------------------------------------------------------------------------
template<int NBLK>
__global__ __launch_bounds__(NTHR_, 2) void fused_plastic(
    const float* __restrict__ inputs,   // [B, IN]
    const float* __restrict__ hidden,   // [B, HS]
    const float* __restrict__ hebb,     // [B, HS, HS]
    const float* __restrict__ i2h_w,    // [HS, IN]
    const float* __restrict__ i2h_b,    // [HS]
    const float* __restrict__ w,        // [HS, HS]
    const float* __restrict__ alpha,    // [HS, HS]
    const float* __restrict__ h2o_w,    // [OUT, HS]
    const float* __restrict__ h2o_b,    // [OUT]
    const float* __restrict__ h2v_w,    // [HS]
    const float* __restrict__ h2v_b,    // [1]
    const float* __restrict__ h2da_w,   // [HS]
    const float* __restrict__ h2da_b,   // [1]
    float* __restrict__ activout,       // [B, OUT]
    float* __restrict__ valueout,       // [B]
    float* __restrict__ hactiv,         // [B, HS]
    float* __restrict__ hebb_new,       // [B, HS, HS]
    float* __restrict__ ws_pd,          // [B*8] per-(sample,block) da partials
    float* __restrict__ ws_pv)          // [B*8] per-(sample,block) value partials
{
    cg::grid_group grid = cg::this_grid();

    constexpr int ROUNDS = 1024 / NBLK;   // 2 (512 blk) or 4 (256 blk)
    constexpr int SPX    = NBLK / 64;     // samples per XCD per round
    constexpr int SPR    = NBLK / 8;      // samples per round

    const int blk  = blockIdx.x;
    const int xcd  = blk & 7;             // heuristic XCD id (perf-only)
    const int slot = blk >> 3;
    const int sub  = slot >> 3;           // sample-within-xcd
    const int bs   = slot & 7;            // block-within-sample (0..7)
    const int tid  = threadIdx.x;
    const int wave = tid >> 6;            // 0..7
    const int lane = tid & 63;

    // LDS: hbB spill store [wave][q][lane] (64 KB) + heads-tail scratch.
    __shared__ float4 s_hbB[NTHR_ * 8];   // 4096 float4 = 64 KB
    __shared__ float  s_h[HS_];
    __shared__ float  s_part[512];
    __shared__ float  s_pd[8];
    __shared__ float  s_pv[8];

    const int i_base = bs * 64 + wave * 8;
    const int sbase  = (wave * 8) * 64 + lane;   // s_hbB slot base for q=0

    for (int r = 0; r < ROUNDS; ++r) {
        const int b = r * SPR + xcd * SPX + sub;

        // Lane-fixed per-sample operands.
        const float4* hid4 = (const float4*)(hidden + (size_t)b * HS_);
        const float4 h0  = hid4[lane];
        const float4 h1  = hid4[lane + 64];
        const float4 in4 = ((const float4*)(inputs + (size_t)b * IN_))[lane];

        // ---- phase 1a: issue ALL 16 hebb loads, park hbB in LDS ----------
        const float* hrow0 = hebb + ((size_t)b * HS_ + i_base) * HS_;
        float4 hbA[8];
        {
            float4 hbT[8];
            #pragma unroll
            for (int q = 0; q < 8; ++q)
                hbA[q] = ((const float4*)(hrow0 + (size_t)q * HS_))[lane];
            #pragma unroll
            for (int q = 0; q < 8; ++q)
                hbT[q] = ((const float4*)(hrow0 + (size_t)q * HS_))[lane + 64];
            #pragma unroll
            for (int q = 0; q < 8; ++q)
                s_hbB[sbase + q * 64] = hbT[q];   // private slot, no barrier
        }

        // ---- phase 1b: row dots (w/alpha/i2h are L2-resident) -------------
        float acc[8];
        #pragma unroll
        for (int q = 0; q < 8; ++q) {
            const int i = i_base + q;
            const float4* wr = (const float4*)(w     + (size_t)i * HS_);
            const float4* ar = (const float4*)(alpha + (size_t)i * HS_);
            const float4 wv0 = wr[lane], wv1 = wr[lane + 64];
            const float4 av0 = ar[lane], av1 = ar[lane + 64];
            const float4 iw  = ((const float4*)(i2h_w + (size_t)i * IN_))[lane];
            const float4 hb1 = s_hbB[sbase + q * 64];

            float a;
            a  = (wv0.x + av0.x * hbA[q].x) * h0.x;
            a += (wv0.y + av0.y * hbA[q].y) * h0.y;
            a += (wv0.z + av0.z * hbA[q].z) * h0.z;
            a += (wv0.w + av0.w * hbA[q].w) * h0.w;
            a += (wv1.x + av1.x * hb1.x) * h1.x;
            a += (wv1.y + av1.y * hb1.y) * h1.y;
            a += (wv1.z + av1.z * hb1.z) * h1.z;
            a += (wv1.w + av1.w * hb1.w) * h1.w;
            a += iw.x * in4.x + iw.y * in4.y + iw.z * in4.z + iw.w * in4.w;
            acc[q] = a;
        }

        // 8 independent butterfly reductions -- chains overlap.
        #pragma unroll
        for (int off = 1; off < 64; off <<= 1) {
            #pragma unroll
            for (int q = 0; q < 8; ++q)
                acc[q] += __shfl_xor(acc[q], off, 64);
        }

        float h_row[8];
        float pd = 0.f, pv = 0.f;
        #pragma unroll
        for (int q = 0; q < 8; ++q) {
            const int i = i_base + q;
            h_row[q] = tanhf(acc[q] + i2h_b[i]);
            if (lane == 0) {
                pd += h_row[q] * h2da_w[i];
                pv += h_row[q] * h2v_w[i];
            }
        }

        // vectorized hactiv store (rows i_base..i_base+7 are consecutive)
        if (lane == 0) {
            float4* hp = (float4*)(hactiv + (size_t)b * HS_ + i_base);
            hp[0] = make_float4(h_row[0], h_row[1], h_row[2], h_row[3]);
            hp[1] = make_float4(h_row[4], h_row[5], h_row[6], h_row[7]);
            s_pd[wave] = pd;
            s_pv[wave] = pv;
        }
        __syncthreads();
        if (tid == 0) {
            float sd = 0.f, sv = 0.f;
            #pragma unroll
            for (int k = 0; k < 8; ++k) { sd += s_pd[k]; sv += s_pv[k]; }
            ws_pd[b * 8 + bs] = sd;
            ws_pv[b * 8 + bs] = sv;
        }
        __threadfence();
        grid.sync();

        // ---- phase 3: finalize da, update hebb (hbA regs + hbB LDS) -------
        float sd = 0.f, sv = 0.f;
        #pragma unroll
        for (int k = 0; k < 8; ++k) {
            sd += ws_pd[b * 8 + k];
            sv += ws_pv[b * 8 + k];
        }
        const float da_b = tanhf(sd + h2da_b[0]);
        if (bs == 0 && tid == 0)
            valueout[b] = sv + h2v_b[0];

        #pragma unroll
        for (int q = 0; q < 8; ++q) {
            const int i = i_base + q;
            const float sc = da_b * h_row[q];
            const float4 hb1 = s_hbB[sbase + q * 64];
            float4 o0, o1;
            o0.x = clip1(fmaf(sc, h0.x, hbA[q].x));
            o0.y = clip1(fmaf(sc, h0.y, hbA[q].y));
            o0.z = clip1(fmaf(sc, h0.z, hbA[q].z));
            o0.w = clip1(fmaf(sc, h0.w, hbA[q].w));
            o1.x = clip1(fmaf(sc, h1.x, hb1.x));
            o1.y = clip1(fmaf(sc, h1.y, hb1.y));
            o1.z = clip1(fmaf(sc, h1.z, hb1.z));
            o1.w = clip1(fmaf(sc, h1.w, hb1.w));
            float4* op = (float4*)(hebb_new + ((size_t)b * HS_ + i) * HS_);
            op[lane]      = o0;
            op[lane + 64] = o1;
        }
    }

    // ---- heads tail: activout (all hactiv visible since last grid.sync) ---
    constexpr int BPS = NBLK / B_;        // blocks per sample (4 or 2)
    constexpr int OPB = OUT_ / BPS;       // outputs per block (64 or 128)
    constexpr int SEG = NTHR_ / OPB;      // dot-segments (8 or 4)
    constexpr int F4S = (HS_ / 4) / SEG;  // float4 per segment (16 or 32)

    const int ba   = blk / BPS;           // sample
    const int part = blk % BPS;           // output chunk

    __syncthreads();
    if (tid < 128)
        ((float4*)s_h)[tid] = ((const float4*)(hactiv + (size_t)ba * HS_))[tid];
    __syncthreads();

    {
        const int ol = tid % OPB;
        const int sg = tid / OPB;
        const int o  = part * OPB + ol;
        const float4* wp  = (const float4*)(h2o_w + (size_t)o * HS_);
        const float4* hp4 = (const float4*)s_h;
        float acc2 = 0.f;
        #pragma unroll
        for (int c = 0; c < F4S; ++c) {
            const float4 wv = wp[sg * F4S + c];
            const float4 hv = hp4[sg * F4S + c];
            acc2 += wv.x * hv.x + wv.y * hv.y + wv.z * hv.z + wv.w * hv.w;
        }
        s_part[sg * OPB + ol] = acc2;
    }
    __syncthreads();
    if (tid < OPB) {
        const int o = part * OPB + tid;
        float acc2 = h2o_b[o];
        #pragma unroll
        for (int k = 0; k < SEG; ++k)
            acc2 += s_part[k * OPB + tid];
        activout[(size_t)ba * OUT_ + o] = acc2;
    }
}

// ---------------------------------------------------------------------------
// Fallback path (original verified 3-kernel version) — used only if the
// workspace is too small for the cooperative path's partials.
// ---------------------------------------------------------------------------
__global__ __launch_bounds__(256) void k1_hactiv(
    const float* __restrict__ inputs, const float* __restrict__ hidden,
    const float* __restrict__ hebb, const float* __restrict__ i2h_w,
    const float* __restrict__ i2h_b, const float* __restrict__ w,
    const float* __restrict__ alpha, float* __restrict__ hactiv)
{
    const int b     = blockIdx.x & (B_ - 1);
    const int chunk = blockIdx.x >> 7;
    const int tid   = threadIdx.x;
    const int wave  = tid >> 6;
    const int lane  = tid & 63;

    const float4* hid4 = (const float4*)(hidden + (size_t)b * HS_);
    const float4  h0   = hid4[lane];
    const float4  h1   = hid4[lane + 64];
    const float4  in4  = ((const float4*)(inputs + (size_t)b * IN_))[lane];

    const int i0 = chunk * 64 + wave * 16;

    for (int r = 0; r < 16; ++r) {
        const int i = i0 + r;
        const float4* hb = (const float4*)(hebb + ((size_t)b * HS_ + i) * HS_);
        const float4* wr = (const float4*)(w     + (size_t)i * HS_);
        const float4* ar = (const float4*)(alpha + (size_t)i * HS_);

        const float4 hb0 = hb[lane];
        const float4 hb1 = hb[lane + 64];
        const float4 wv0 = wr[lane];
        const float4 wv1 = wr[lane + 64];
        const float4 av0 = ar[lane];
        const float4 av1 = ar[lane + 64];
        const float4 iw  = ((const float4*)(i2h_w + (size_t)i * IN_))[lane];

        float acc;
        acc  = (wv0.x + av0.x * hb0.x) * h0.x;
        acc += (wv0.y + av0.y * hb0.y) * h0.y;
        acc += (wv0.z + av0.z * hb0.z) * h0.z;
        acc += (wv0.w + av0.w * hb0.w) * h0.w;
        acc += (wv1.x + av1.x * hb1.x) * h1.x;
        acc += (wv1.y + av1.y * hb1.y) * h1.y;
        acc += (wv1.z + av1.z * hb1.z) * h1.z;
        acc += (wv1.w + av1.w * hb1.w) * h1.w;
        acc += iw.x * in4.x + iw.y * in4.y + iw.z * in4.z + iw.w * in4.w;

        #pragma unroll
        for (int off = 32; off > 0; off >>= 1)
            acc += __shfl_down(acc, off, 64);

        if (lane == 0)
            hactiv[(size_t)b * HS_ + i] = tanhf(acc + i2h_b[i]);
    }
}

__global__ __launch_bounds__(256) void k2_heads(
    const float* __restrict__ hactiv, const float* __restrict__ h2o_w,
    const float* __restrict__ h2o_b, const float* __restrict__ h2v_w,
    const float* __restrict__ h2v_b, const float* __restrict__ h2da_w,
    const float* __restrict__ h2da_b, float* __restrict__ activout,
    float* __restrict__ valueout, float* __restrict__ da)
{
    const int b   = blockIdx.x;
    const int tid = threadIdx.x;

    __shared__ float s_h[HS_];
    __shared__ float red_v[256];
    __shared__ float red_d[256];

    for (int t = tid; t < HS_; t += 256)
        s_h[t] = hactiv[(size_t)b * HS_ + t];
    __syncthreads();

    const float4* wr  = (const float4*)(h2o_w + (size_t)tid * HS_);
    const float4* sh4 = (const float4*)s_h;
    float acc = 0.f;
    #pragma unroll 4
    for (int q = 0; q < HS_ / 4; ++q) {
        const float4 wv = wr[q];
        const float4 hv = sh4[q];
        acc += wv.x * hv.x + wv.y * hv.y + wv.z * hv.z + wv.w * hv.w;
    }
    activout[(size_t)b * OUT_ + tid] = acc + h2o_b[tid];

    float pv = 0.f, pd = 0.f;
    for (int t = tid; t < HS_; t += 256) {
        const float hv = s_h[t];
        pv += hv * h2v_w[t];
        pd += hv * h2da_w[t];
    }
    red_v[tid] = pv;
    red_d[tid] = pd;
    __syncthreads();
    for (int s = 128; s > 0; s >>= 1) {
        if (tid < s) {
            red_v[tid] += red_v[tid + s];
            red_d[tid] += red_d[tid + s];
        }
        __syncthreads();
    }
    if (tid == 0) {
        valueout[b] = red_v[0] + h2v_b[0];
        da[b]       = tanhf(red_d[0] + h2da_b[0]);
    }
}

__global__ __launch_bounds__(256) void k3_hebb(
    const float* __restrict__ hebb, const float* __restrict__ hidden,
    const float* __restrict__ hactiv, const float* __restrict__ da,
    float* __restrict__ hebb_new)
{
    const int tid = threadIdx.x;
    const size_t base = (size_t)blockIdx.x * 1024;

    #pragma unroll
    for (int k = 0; k < 4; ++k) {
        const size_t idx = base + (size_t)k * 256 + tid;
        const int j4  = (int)(idx & 127);
        const int row = (int)(idx >> 7);
        const int i   = row & (HS_ - 1);
        const int b   = row >> 9;

        const float scale = da[b] * hactiv[(size_t)b * HS_ + i];
        const float4 hv = ((const float4*)hebb)[idx];
        const float4 hd = ((const float4*)hidden)[(size_t)b * (HS_ / 4) + j4];

        float4 r;
        r.x = fminf(fmaxf(fmaf(scale, hd.x, hv.x), -1.f), 1.f);
        r.y = fminf(fmaxf(fmaf(scale, hd.y, hv.y), -1.f), 1.f);
        r.z = fminf(fmaxf(fmaf(scale, hd.z, hv.z), -1.f), 1.f);
        r.w = fminf(fmaxf(fmaf(scale, hd.w, hv.w), -1.f), 1.f);
        ((float4*)hebb_new)[idx] = r;
    }
}

// ---------------------------------------------------------------------------
extern "C" void kernel_launch(void* const* d_in, const int* in_sizes, int n_in,
                              void* d_out, int out_size, void* d_ws, size_t ws_size,
                              hipStream_t stream)
{
    const float* inputs = (const float*)d_in[0];
    const float* hidden = (const float*)d_in[1];
    const float* hebb   = (const float*)d_in[2];
    const float* i2h_w  = (const float*)d_in[3];
    const float* i2h_b  = (const float*)d_in[4];
    const float* w      = (const float*)d_in[5];
    const float* alpha  = (const float*)d_in[6];
    const float* h2o_w  = (const float*)d_in[7];
    const float* h2o_b  = (const float*)d_in[8];
    const float* h2v_w  = (const float*)d_in[9];
    const float* h2v_b  = (const float*)d_in[10];
    const float* h2da_w = (const float*)d_in[11];
    const float* h2da_b = (const float*)d_in[12];

    float* out = (float*)d_out;
    // Output layout (flat, return order): activout | valueout | hactiv | hebb_new
    float* activout = out;                              // 128*256   = 32768
    float* valueout = out + 32768;                      // 128
    float* hactiv   = out + 32768 + 128;                // 128*512   = 65536
    float* hebb_new = out + 32768 + 128 + 65536;        // 128*512*512

    if (ws_size >= (size_t)(2 * B_ * 8 * sizeof(float))) {
        float* ws_pd = (float*)d_ws;                    // [128*8]
        float* ws_pv = ws_pd + B_ * 8;                  // [128*8]

        void* args[] = {
            (void*)&inputs, (void*)&hidden, (void*)&hebb, (void*)&i2h_w,
            (void*)&i2h_b,  (void*)&w,      (void*)&alpha, (void*)&h2o_w,
            (void*)&h2o_b,  (void*)&h2v_w,  (void*)&h2v_b, (void*)&h2da_w,
            (void*)&h2da_b, (void*)&activout, (void*)&valueout,
            (void*)&hactiv, (void*)&hebb_new, (void*)&ws_pd, (void*)&ws_pv
        };

        // Prefer 2 blocks/CU (512 blocks); occupancy-query guard so the
        // cooperative launch can never exceed co-residency.
        int maxb = 0;
        hipError_t oe = hipOccupancyMaxActiveBlocksPerMultiprocessor(
            &maxb, fused_plastic<512>, NTHR_, 0);
        if (oe == hipSuccess && maxb >= 2) {
            hipLaunchCooperativeKernel((const void*)fused_plastic<512>,
                                       dim3(512), dim3(NTHR_), args, 0, stream);
        } else {
            hipLaunchCooperativeKernel((const void*)fused_plastic<256>,
                                       dim3(256), dim3(NTHR_), args, 0, stream);
        }
    } else {
        float* da = (float*)d_ws;                       // [128] scratch
        k1_hactiv<<<dim3(1024), dim3(256), 0, stream>>>(
            inputs, hidden, hebb, i2h_w, i2h_b, w, alpha, hactiv);
        k2_heads<<<dim3(B_), dim3(256), 0, stream>>>(
            hactiv, h2o_w, h2o_b, h2v_w, h2v_b, h2da_w, h2da_b,
            activout, valueout, da);
        k3_hebb<<<dim3(8192), dim3(256), 0, stream>>>(
            hebb, hidden, hactiv, da, hebb_new);
    }
}

// Round 4
// 327.400 us; speedup vs baseline: 2.3981x; 1.8178x over previous
//
#include <hip/hip_runtime.h>
#include <cstddef>
#include <cstdint>

// Problem constants (all powers of two).
#define B_    128
#define IN_   256
#define OUT_  256
#define HS_   512

#define NTHR_  512
#define NBLK_  512
#define SPLIT_ 4      // blocks per sample

__device__ __forceinline__ float clip1(float x) {
    return fminf(fmaxf(x, -1.f), 1.f);
}

// ---------------------------------------------------------------------------
// Streaming fused kernel. 512 blocks x 512 threads, 2 blocks/CU (VGPR<=128,
// ~4 KB LDS). 4 sibling blocks own one sample (128 rows each; 8 waves x 16
// rows). No grid.sync: siblings exchange da/value partials through the
// workspace with release/acquire atomics and a tiny spin. Siblings are
// within a 32-slot dispatch window and the whole grid is co-resident at
// 2 blocks/CU, so the spin cannot deadlock.
//
// Pass 1: stream hebb+w+alpha (7 independent float4 loads per row, 2-row
//         unroll, no barriers) -> hactiv rows (kept in LDS) + partials.
// Pass 2: re-stream hebb (L3-resident: 134 MB < 256 MB Infinity Cache) and
//         write hebb_new. Then the activout head from L2-cached h2o_w.
// ---------------------------------------------------------------------------
__global__ __launch_bounds__(NTHR_, 2) void fused_stream(
    const float* __restrict__ inputs,   // [B, IN]
    const float* __restrict__ hidden,   // [B, HS]
    const float* __restrict__ hebb,     // [B, HS, HS]
    const float* __restrict__ i2h_w,    // [HS, IN]
    const float* __restrict__ i2h_b,    // [HS]
    const float* __restrict__ w,        // [HS, HS]
    const float* __restrict__ alpha,    // [HS, HS]
    const float* __restrict__ h2o_w,    // [OUT, HS]
    const float* __restrict__ h2o_b,    // [OUT]
    const float* __restrict__ h2v_w,    // [HS]
    const float* __restrict__ h2v_b,    // [1]
    const float* __restrict__ h2da_w,   // [HS]
    const float* __restrict__ h2da_b,   // [1]
    float* __restrict__ activout,       // [B, OUT]
    float* __restrict__ valueout,       // [B]
    float* __restrict__ hactiv,         // [B, HS]
    float* __restrict__ hebb_new,       // [B, HS, HS]
    float* __restrict__ ws_pd,          // [B] da partial (atomic accum)
    float* __restrict__ ws_pv,          // [B] value partial (atomic accum)
    int*   __restrict__ ws_cnt)         // [B] arrival counter
{
    // XCD-grouped mapping: siblings of a sample share an XCD (round-robin
    // dispatch heuristic, perf-only; correctness uses device-scope atomics).
    const int blk  = blockIdx.x;
    const int xcd  = blk & 7;
    const int g    = blk >> 3;          // 0..63
    const int q16  = g >> 2;            // 0..15
    const int s    = g & 3;             // sibling index 0..3
    const int b    = xcd * 16 + q16;    // sample
    const int tid  = threadIdx.x;
    const int wave = tid >> 6;          // 0..7
    const int lane = tid & 63;
    const int r0   = s * 128 + wave * 16;   // first global row of this wave
    const int lr0  = wave * 16;             // first block-local row

    __shared__ float s_hrow[128];       // this block's hactiv rows
    __shared__ float s_pd[8], s_pv[8];
    __shared__ float s_bc[2];           // broadcast: da, value
    __shared__ float s_h[HS_];          // full hactiv[b] for the head
    __shared__ float s_part[256];

    // Lane-fixed per-sample operands.
    const float4* hid4 = (const float4*)(hidden + (size_t)b * HS_);
    const float4 h0  = hid4[lane];
    const float4 h1  = hid4[lane + 64];
    const float4 in4 = ((const float4*)(inputs + (size_t)b * IN_))[lane];

    const float4* hb4 = (const float4*)hebb + ((size_t)b * HS_) * (HS_ / 4);
    const float4* w4  = (const float4*)w;
    const float4* a4  = (const float4*)alpha;
    const float4* iw4 = (const float4*)i2h_w;

    // ---- pass 1: stream hebb/w/alpha, compute hactiv rows ----------------
    float pd = 0.f, pv = 0.f;
    for (int t = 0; t < 16; t += 2) {
        const int i = r0 + t;
        const float4* hpA = hb4 + (size_t)i * (HS_ / 4);
        const float4* hpB = hpA + (HS_ / 4);
        const float4* wpA = w4  + (size_t)i * (HS_ / 4);
        const float4* apA = a4  + (size_t)i * (HS_ / 4);
        const float4* ipA = iw4 + (size_t)i * (IN_ / 4);

        // 14 independent float4 loads (streaming; compiler keeps in flight)
        const float4 xA0 = hpA[lane],            xA1 = hpA[lane + 64];
        const float4 xB0 = hpB[lane],            xB1 = hpB[lane + 64];
        const float4 wA0 = wpA[lane],            wA1 = wpA[lane + 64];
        const float4 wB0 = wpA[128 + lane],      wB1 = wpA[128 + lane + 64];
        const float4 aA0 = apA[lane],            aA1 = apA[lane + 64];
        const float4 aB0 = apA[128 + lane],      aB1 = apA[128 + lane + 64];
        const float4 iA  = ipA[lane];
        const float4 iB  = ipA[64 + lane];

        float a, c;
        a  = (wA0.x + aA0.x * xA0.x) * h0.x;
        a += (wA0.y + aA0.y * xA0.y) * h0.y;
        a += (wA0.z + aA0.z * xA0.z) * h0.z;
        a += (wA0.w + aA0.w * xA0.w) * h0.w;
        a += (wA1.x + aA1.x * xA1.x) * h1.x;
        a += (wA1.y + aA1.y * xA1.y) * h1.y;
        a += (wA1.z + aA1.z * xA1.z) * h1.z;
        a += (wA1.w + aA1.w * xA1.w) * h1.w;
        a += iA.x * in4.x + iA.y * in4.y + iA.z * in4.z + iA.w * in4.w;

        c  = (wB0.x + aB0.x * xB0.x) * h0.x;
        c += (wB0.y + aB0.y * xB0.y) * h0.y;
        c += (wB0.z + aB0.z * xB0.z) * h0.z;
        c += (wB0.w + aB0.w * xB0.w) * h0.w;
        c += (wB1.x + aB1.x * xB1.x) * h1.x;
        c += (wB1.y + aB1.y * xB1.y) * h1.y;
        c += (wB1.z + aB1.z * xB1.z) * h1.z;
        c += (wB1.w + aB1.w * xB1.w) * h1.w;
        c += iB.x * in4.x + iB.y * in4.y + iB.z * in4.z + iB.w * in4.w;

        // two independent 6-step butterflies (chains overlap)
        #pragma unroll
        for (int off = 1; off < 64; off <<= 1) {
            a += __shfl_xor(a, off, 64);
            c += __shfl_xor(c, off, 64);
        }

        const float hA = tanhf(a + i2h_b[i]);
        const float hB = tanhf(c + i2h_b[i + 1]);
        if (lane == 0) {
            s_hrow[lr0 + t]     = hA;
            s_hrow[lr0 + t + 1] = hB;
            float2* hp = (float2*)(hactiv + (size_t)b * HS_ + i);
            *hp = make_float2(hA, hB);
            pd += hA * h2da_w[i] + hB * h2da_w[i + 1];
            pv += hA * h2v_w[i]  + hB * h2v_w[i + 1];
        }
    }

    if (lane == 0) { s_pd[wave] = pd; s_pv[wave] = pv; }
    __syncthreads();

    // ---- gate: post partials (release), spin for 4 siblings (acquire) ----
    if (tid == 0) {
        float sd = 0.f, sv = 0.f;
        #pragma unroll
        for (int k = 0; k < 8; ++k) { sd += s_pd[k]; sv += s_pv[k]; }
        __hip_atomic_fetch_add(&ws_pd[b], sd, __ATOMIC_RELAXED,
                               __HIP_MEMORY_SCOPE_AGENT);
        __hip_atomic_fetch_add(&ws_pv[b], sv, __ATOMIC_RELAXED,
                               __HIP_MEMORY_SCOPE_AGENT);
        __hip_atomic_fetch_add(&ws_cnt[b], 1, __ATOMIC_RELEASE,
                               __HIP_MEMORY_SCOPE_AGENT);
        while (__hip_atomic_load(&ws_cnt[b], __ATOMIC_ACQUIRE,
                                 __HIP_MEMORY_SCOPE_AGENT) < SPLIT_)
            __builtin_amdgcn_s_sleep(1);
        const float pdt = __hip_atomic_load(&ws_pd[b], __ATOMIC_RELAXED,
                                            __HIP_MEMORY_SCOPE_AGENT);
        const float pvt = __hip_atomic_load(&ws_pv[b], __ATOMIC_RELAXED,
                                            __HIP_MEMORY_SCOPE_AGENT);
        s_bc[0] = tanhf(pdt + h2da_b[0]);
        s_bc[1] = pvt + h2v_b[0];
    }
    __syncthreads();
    const float da_b = s_bc[0];
    if (s == 0 && tid == 0)
        valueout[b] = s_bc[1];

    // ---- pass 2: re-stream hebb (L3 hits), write hebb_new ----------------
    for (int t = 0; t < 16; t += 2) {
        const int i = r0 + t;
        const float4* xp = hb4 + (size_t)i * (HS_ / 4);
        const float4 x0 = xp[lane],       x1 = xp[lane + 64];
        const float4 y0 = xp[128 + lane], y1 = xp[128 + lane + 64];
        const float scA = da_b * s_hrow[lr0 + t];
        const float scB = da_b * s_hrow[lr0 + t + 1];

        float4 o0, o1, p0, p1;
        o0.x = clip1(fmaf(scA, h0.x, x0.x));
        o0.y = clip1(fmaf(scA, h0.y, x0.y));
        o0.z = clip1(fmaf(scA, h0.z, x0.z));
        o0.w = clip1(fmaf(scA, h0.w, x0.w));
        o1.x = clip1(fmaf(scA, h1.x, x1.x));
        o1.y = clip1(fmaf(scA, h1.y, x1.y));
        o1.z = clip1(fmaf(scA, h1.z, x1.z));
        o1.w = clip1(fmaf(scA, h1.w, x1.w));
        p0.x = clip1(fmaf(scB, h0.x, y0.x));
        p0.y = clip1(fmaf(scB, h0.y, y0.y));
        p0.z = clip1(fmaf(scB, h0.z, y0.z));
        p0.w = clip1(fmaf(scB, h0.w, y0.w));
        p1.x = clip1(fmaf(scB, h1.x, y1.x));
        p1.y = clip1(fmaf(scB, h1.y, y1.y));
        p1.z = clip1(fmaf(scB, h1.z, y1.z));
        p1.w = clip1(fmaf(scB, h1.w, y1.w));

        float4* dp = (float4*)hebb_new + ((size_t)b * HS_ + i) * (HS_ / 4);
        dp[lane]            = o0;
        dp[lane + 64]       = o1;
        dp[128 + lane]      = p0;
        dp[128 + lane + 64] = p1;
    }

    // ---- head: activout (this block does its quarter of the outputs) -----
    if (tid < 128)
        ((float4*)s_h)[tid] = ((const float4*)(hactiv + (size_t)b * HS_))[tid];
    __syncthreads();

    if (tid < 256) {
        const int ol = tid & 63;
        const int qq = tid >> 6;            // 0..3 quarter of the dot
        const int o  = s * 64 + ol;
        const float4* wp  = (const float4*)(h2o_w + (size_t)o * HS_);
        const float4* hp4 = (const float4*)s_h;
        float acc = 0.f;
        #pragma unroll
        for (int c2 = 0; c2 < 32; ++c2) {
            const float4 wv = wp[qq * 32 + c2];
            const float4 hv = hp4[qq * 32 + c2];
            acc += wv.x * hv.x + wv.y * hv.y + wv.z * hv.z + wv.w * hv.w;
        }
        s_part[qq * 64 + ol] = acc;
    }
    __syncthreads();
    if (tid < 64) {
        const int o = s * 64 + tid;
        activout[(size_t)b * OUT_ + o] =
            s_part[tid] + s_part[64 + tid] + s_part[128 + tid] +
            s_part[192 + tid] + h2o_b[o];
    }
}

// ---------------------------------------------------------------------------
// Fallback path (original verified 3-kernel version) — used only if the
// workspace is too small for the gate counters (1.5 KB).
// ---------------------------------------------------------------------------
__global__ __launch_bounds__(256) void k1_hactiv(
    const float* __restrict__ inputs, const float* __restrict__ hidden,
    const float* __restrict__ hebb, const float* __restrict__ i2h_w,
    const float* __restrict__ i2h_b, const float* __restrict__ w,
    const float* __restrict__ alpha, float* __restrict__ hactiv)
{
    const int b     = blockIdx.x & (B_ - 1);
    const int chunk = blockIdx.x >> 7;
    const int tid   = threadIdx.x;
    const int wave  = tid >> 6;
    const int lane  = tid & 63;

    const float4* hid4 = (const float4*)(hidden + (size_t)b * HS_);
    const float4  h0   = hid4[lane];
    const float4  h1   = hid4[lane + 64];
    const float4  in4  = ((const float4*)(inputs + (size_t)b * IN_))[lane];

    const int i0 = chunk * 64 + wave * 16;

    for (int r = 0; r < 16; ++r) {
        const int i = i0 + r;
        const float4* hb = (const float4*)(hebb + ((size_t)b * HS_ + i) * HS_);
        const float4* wr = (const float4*)(w     + (size_t)i * HS_);
        const float4* ar = (const float4*)(alpha + (size_t)i * HS_);

        const float4 hb0 = hb[lane];
        const float4 hb1 = hb[lane + 64];
        const float4 wv0 = wr[lane];
        const float4 wv1 = wr[lane + 64];
        const float4 av0 = ar[lane];
        const float4 av1 = ar[lane + 64];
        const float4 iw  = ((const float4*)(i2h_w + (size_t)i * IN_))[lane];

        float acc;
        acc  = (wv0.x + av0.x * hb0.x) * h0.x;
        acc += (wv0.y + av0.y * hb0.y) * h0.y;
        acc += (wv0.z + av0.z * hb0.z) * h0.z;
        acc += (wv0.w + av0.w * hb0.w) * h0.w;
        acc += (wv1.x + av1.x * hb1.x) * h1.x;
        acc += (wv1.y + av1.y * hb1.y) * h1.y;
        acc += (wv1.z + av1.z * hb1.z) * h1.z;
        acc += (wv1.w + av1.w * hb1.w) * h1.w;
        acc += iw.x * in4.x + iw.y * in4.y + iw.z * in4.z + iw.w * in4.w;

        #pragma unroll
        for (int off = 32; off > 0; off >>= 1)
            acc += __shfl_down(acc, off, 64);

        if (lane == 0)
            hactiv[(size_t)b * HS_ + i] = tanhf(acc + i2h_b[i]);
    }
}

__global__ __launch_bounds__(256) void k2_heads(
    const float* __restrict__ hactiv, const float* __restrict__ h2o_w,
    const float* __restrict__ h2o_b, const float* __restrict__ h2v_w,
    const float* __restrict__ h2v_b, const float* __restrict__ h2da_w,
    const float* __restrict__ h2da_b, float* __restrict__ activout,
    float* __restrict__ valueout, float* __restrict__ da)
{
    const int b   = blockIdx.x;
    const int tid = threadIdx.x;

    __shared__ float s_h[HS_];
    __shared__ float red_v[256];
    __shared__ float red_d[256];

    for (int t = tid; t < HS_; t += 256)
        s_h[t] = hactiv[(size_t)b * HS_ + t];
    __syncthreads();

    const float4* wr  = (const float4*)(h2o_w + (size_t)tid * HS_);
    const float4* sh4 = (const float4*)s_h;
    float acc = 0.f;
    #pragma unroll 4
    for (int q = 0; q < HS_ / 4; ++q) {
        const float4 wv = wr[q];
        const float4 hv = sh4[q];
        acc += wv.x * hv.x + wv.y * hv.y + wv.z * hv.z + wv.w * hv.w;
    }
    activout[(size_t)b * OUT_ + tid] = acc + h2o_b[tid];

    float pv = 0.f, pd = 0.f;
    for (int t = tid; t < HS_; t += 256) {
        const float hv = s_h[t];
        pv += hv * h2v_w[t];
        pd += hv * h2da_w[t];
    }
    red_v[tid] = pv;
    red_d[tid] = pd;
    __syncthreads();
    for (int s2 = 128; s2 > 0; s2 >>= 1) {
        if (tid < s2) {
            red_v[tid] += red_v[tid + s2];
            red_d[tid] += red_d[tid + s2];
        }
        __syncthreads();
    }
    if (tid == 0) {
        valueout[b] = red_v[0] + h2v_b[0];
        da[b]       = tanhf(red_d[0] + h2da_b[0]);
    }
}

__global__ __launch_bounds__(256) void k3_hebb(
    const float* __restrict__ hebb, const float* __restrict__ hidden,
    const float* __restrict__ hactiv, const float* __restrict__ da,
    float* __restrict__ hebb_new)
{
    const int tid = threadIdx.x;
    const size_t base = (size_t)blockIdx.x * 1024;

    #pragma unroll
    for (int k = 0; k < 4; ++k) {
        const size_t idx = base + (size_t)k * 256 + tid;
        const int j4  = (int)(idx & 127);
        const int row = (int)(idx >> 7);
        const int i   = row & (HS_ - 1);
        const int b   = row >> 9;

        const float scale = da[b] * hactiv[(size_t)b * HS_ + i];
        const float4 hv = ((const float4*)hebb)[idx];
        const float4 hd = ((const float4*)hidden)[(size_t)b * (HS_ / 4) + j4];

        float4 r;
        r.x = fminf(fmaxf(fmaf(scale, hd.x, hv.x), -1.f), 1.f);
        r.y = fminf(fmaxf(fmaf(scale, hd.y, hv.y), -1.f), 1.f);
        r.z = fminf(fmaxf(fmaf(scale, hd.z, hv.z), -1.f), 1.f);
        r.w = fminf(fmaxf(fmaf(scale, hd.w, hv.w), -1.f), 1.f);
        ((float4*)hebb_new)[idx] = r;
    }
}

// ---------------------------------------------------------------------------
extern "C" void kernel_launch(void* const* d_in, const int* in_sizes, int n_in,
                              void* d_out, int out_size, void* d_ws, size_t ws_size,
                              hipStream_t stream)
{
    const float* inputs = (const float*)d_in[0];
    const float* hidden = (const float*)d_in[1];
    const float* hebb   = (const float*)d_in[2];
    const float* i2h_w  = (const float*)d_in[3];
    const float* i2h_b  = (const float*)d_in[4];
    const float* w      = (const float*)d_in[5];
    const float* alpha  = (const float*)d_in[6];
    const float* h2o_w  = (const float*)d_in[7];
    const float* h2o_b  = (const float*)d_in[8];
    const float* h2v_w  = (const float*)d_in[9];
    const float* h2v_b  = (const float*)d_in[10];
    const float* h2da_w = (const float*)d_in[11];
    const float* h2da_b = (const float*)d_in[12];

    float* out = (float*)d_out;
    // Output layout (flat, return order): activout | valueout | hactiv | hebb_new
    float* activout = out;                              // 128*256   = 32768
    float* valueout = out + 32768;                      // 128
    float* hactiv   = out + 32768 + 128;                // 128*512   = 65536
    float* hebb_new = out + 32768 + 128 + 65536;        // 128*512*512

    const size_t gate_bytes = (size_t)(3 * B_) * sizeof(float);   // 1.5 KB

    if (ws_size >= gate_bytes) {
        float* ws_pd  = (float*)d_ws;                   // [128]
        float* ws_pv  = ws_pd + B_;                     // [128]
        int*   ws_cnt = (int*)(ws_pv + B_);             // [128]

        // Zero the gate state each launch (graph-capturable stream op).
        hipMemsetAsync(d_ws, 0, gate_bytes, stream);

        fused_stream<<<dim3(NBLK_), dim3(NTHR_), 0, stream>>>(
            inputs, hidden, hebb, i2h_w, i2h_b, w, alpha,
            h2o_w, h2o_b, h2v_w, h2v_b, h2da_w, h2da_b,
            activout, valueout, hactiv, hebb_new,
            ws_pd, ws_pv, ws_cnt);
    } else {
        float* da = (float*)d_ws;                       // [128] scratch
        k1_hactiv<<<dim3(1024), dim3(256), 0, stream>>>(
            inputs, hidden, hebb, i2h_w, i2h_b, w, alpha, hactiv);
        k2_heads<<<dim3(B_), dim3(256), 0, stream>>>(
            hactiv, h2o_w, h2o_b, h2v_w, h2v_b, h2da_w, h2da_b,
            activout, valueout, da);
        k3_hebb<<<dim3(8192), dim3(256), 0, stream>>>(
            hebb, hidden, hactiv, da, hebb_new);
    }
}

// Round 5
// 299.651 us; speedup vs baseline: 2.6201x; 1.0926x over previous
//
#include <hip/hip_runtime.h>
#include <cstddef>
#include <cstdint>

// Problem constants (all powers of two).
#define B_    128
#define IN_   256
#define OUT_  256
#define HS_   512

#define NTHR_  512
#define NBLK_  1024
#define SPLIT_ 8      // sibling blocks per sample

__device__ __forceinline__ float clip1(float x) {
    return fminf(fmaxf(x, -1.f), 1.f);
}

// ---------------------------------------------------------------------------
// Streaming fused kernel at MAX occupancy. 1024 blocks x 512 threads =
// 4 blocks/CU = 32 waves/CU (hardware max). launch_bounds(512,4) caps the
// allocation at 64 VGPR (round-2/4 empirical: the round-4 body compiles to
// exactly 64), and LDS ~4 KB/block, so 4 blocks/CU are guaranteed resident
// -> the sibling spin-gate cannot deadlock (guarded further by an occupancy
// query at launch).
//
// 8 sibling blocks own one sample (64 rows each; 8 waves x 8 rows).
// Pass 1: stream hebb+w+alpha (14 independent float4 loads per 2-row
//         iteration, no barriers) -> hactiv rows (LDS) + da/value partials.
// Gate:   siblings exchange partials via device-scope atomics + spin.
// Pass 2: re-stream hebb (L3-resident; round-4 FETCH=146MB confirms L3
//         absorbs the re-read) and write hebb_new. Then the activout head.
// ---------------------------------------------------------------------------
__global__ __launch_bounds__(NTHR_, 4) void fused_stream(
    const float* __restrict__ inputs,   // [B, IN]
    const float* __restrict__ hidden,   // [B, HS]
    const float* __restrict__ hebb,     // [B, HS, HS]
    const float* __restrict__ i2h_w,    // [HS, IN]
    const float* __restrict__ i2h_b,    // [HS]
    const float* __restrict__ w,        // [HS, HS]
    const float* __restrict__ alpha,    // [HS, HS]
    const float* __restrict__ h2o_w,    // [OUT, HS]
    const float* __restrict__ h2o_b,    // [OUT]
    const float* __restrict__ h2v_w,    // [HS]
    const float* __restrict__ h2v_b,    // [1]
    const float* __restrict__ h2da_w,   // [HS]
    const float* __restrict__ h2da_b,   // [1]
    float* __restrict__ activout,       // [B, OUT]
    float* __restrict__ valueout,       // [B]
    float* __restrict__ hactiv,         // [B, HS]
    float* __restrict__ hebb_new,       // [B, HS, HS]
    float* __restrict__ ws_pd,          // [B] da partial (atomic accum)
    float* __restrict__ ws_pv,          // [B] value partial (atomic accum)
    int*   __restrict__ ws_cnt)         // [B] arrival counter
{
    const int blk  = blockIdx.x;
    const int b    = blk >> 3;          // sample 0..127 (siblings adjacent ->
    const int s    = blk & 7;           //   near-simultaneous dispatch)
    const int tid  = threadIdx.x;
    const int wave = tid >> 6;          // 0..7
    const int lane = tid & 63;
    const int r0   = s * 64 + wave * 8; // first global row of this wave
    const int lr0  = wave * 8;          // first block-local row

    __shared__ float s_hrow[64];        // this block's hactiv rows
    __shared__ float s_pd[8], s_pv[8];
    __shared__ float s_bc[2];           // broadcast: da, value
    __shared__ float s_h[HS_];          // full hactiv[b] for the head
    __shared__ float s_part[512];

    // Lane-fixed per-sample operands.
    const float4* hid4 = (const float4*)(hidden + (size_t)b * HS_);
    const float4 h0  = hid4[lane];
    const float4 h1  = hid4[lane + 64];
    const float4 in4 = ((const float4*)(inputs + (size_t)b * IN_))[lane];

    const float4* hb4 = (const float4*)hebb + ((size_t)b * HS_) * (HS_ / 4);
    const float4* w4  = (const float4*)w;
    const float4* a4  = (const float4*)alpha;
    const float4* iw4 = (const float4*)i2h_w;

    // ---- pass 1: stream hebb/w/alpha, compute hactiv rows ----------------
    float pd = 0.f, pv = 0.f;
    for (int t = 0; t < 8; t += 2) {
        const int i = r0 + t;
        const float4* hpA = hb4 + (size_t)i * (HS_ / 4);
        const float4* hpB = hpA + (HS_ / 4);
        const float4* wpA = w4  + (size_t)i * (HS_ / 4);
        const float4* apA = a4  + (size_t)i * (HS_ / 4);
        const float4* ipA = iw4 + (size_t)i * (IN_ / 4);

        // 14 independent float4 loads
        const float4 xA0 = hpA[lane],            xA1 = hpA[lane + 64];
        const float4 xB0 = hpB[lane],            xB1 = hpB[lane + 64];
        const float4 wA0 = wpA[lane],            wA1 = wpA[lane + 64];
        const float4 wB0 = wpA[128 + lane],      wB1 = wpA[128 + lane + 64];
        const float4 aA0 = apA[lane],            aA1 = apA[lane + 64];
        const float4 aB0 = apA[128 + lane],      aB1 = apA[128 + lane + 64];
        const float4 iA  = ipA[lane];
        const float4 iB  = ipA[64 + lane];

        float a, c;
        a  = (wA0.x + aA0.x * xA0.x) * h0.x;
        a += (wA0.y + aA0.y * xA0.y) * h0.y;
        a += (wA0.z + aA0.z * xA0.z) * h0.z;
        a += (wA0.w + aA0.w * xA0.w) * h0.w;
        a += (wA1.x + aA1.x * xA1.x) * h1.x;
        a += (wA1.y + aA1.y * xA1.y) * h1.y;
        a += (wA1.z + aA1.z * xA1.z) * h1.z;
        a += (wA1.w + aA1.w * xA1.w) * h1.w;
        a += iA.x * in4.x + iA.y * in4.y + iA.z * in4.z + iA.w * in4.w;

        c  = (wB0.x + aB0.x * xB0.x) * h0.x;
        c += (wB0.y + aB0.y * xB0.y) * h0.y;
        c += (wB0.z + aB0.z * xB0.z) * h0.z;
        c += (wB0.w + aB0.w * xB0.w) * h0.w;
        c += (wB1.x + aB1.x * xB1.x) * h1.x;
        c += (wB1.y + aB1.y * xB1.y) * h1.y;
        c += (wB1.z + aB1.z * xB1.z) * h1.z;
        c += (wB1.w + aB1.w * xB1.w) * h1.w;
        c += iB.x * in4.x + iB.y * in4.y + iB.z * in4.z + iB.w * in4.w;

        // two independent 6-step butterflies (chains overlap)
        #pragma unroll
        for (int off = 1; off < 64; off <<= 1) {
            a += __shfl_xor(a, off, 64);
            c += __shfl_xor(c, off, 64);
        }

        const float hA = tanhf(a + i2h_b[i]);
        const float hB = tanhf(c + i2h_b[i + 1]);
        if (lane == 0) {
            s_hrow[lr0 + t]     = hA;
            s_hrow[lr0 + t + 1] = hB;
            float2* hp = (float2*)(hactiv + (size_t)b * HS_ + i);
            *hp = make_float2(hA, hB);
            pd += hA * h2da_w[i] + hB * h2da_w[i + 1];
            pv += hA * h2v_w[i]  + hB * h2v_w[i + 1];
        }
    }

    if (lane == 0) { s_pd[wave] = pd; s_pv[wave] = pv; }
    __syncthreads();

    // ---- gate: post partials (release), spin for 8 siblings (acquire) ----
    if (tid == 0) {
        float sd = 0.f, sv = 0.f;
        #pragma unroll
        for (int k = 0; k < 8; ++k) { sd += s_pd[k]; sv += s_pv[k]; }
        __hip_atomic_fetch_add(&ws_pd[b], sd, __ATOMIC_RELAXED,
                               __HIP_MEMORY_SCOPE_AGENT);
        __hip_atomic_fetch_add(&ws_pv[b], sv, __ATOMIC_RELAXED,
                               __HIP_MEMORY_SCOPE_AGENT);
        __hip_atomic_fetch_add(&ws_cnt[b], 1, __ATOMIC_RELEASE,
                               __HIP_MEMORY_SCOPE_AGENT);
        while (__hip_atomic_load(&ws_cnt[b], __ATOMIC_ACQUIRE,
                                 __HIP_MEMORY_SCOPE_AGENT) < SPLIT_)
            __builtin_amdgcn_s_sleep(1);
        const float pdt = __hip_atomic_load(&ws_pd[b], __ATOMIC_RELAXED,
                                            __HIP_MEMORY_SCOPE_AGENT);
        const float pvt = __hip_atomic_load(&ws_pv[b], __ATOMIC_RELAXED,
                                            __HIP_MEMORY_SCOPE_AGENT);
        s_bc[0] = tanhf(pdt + h2da_b[0]);
        s_bc[1] = pvt + h2v_b[0];
    }
    __syncthreads();
    const float da_b = s_bc[0];
    if (s == 0 && tid == 0)
        valueout[b] = s_bc[1];

    // ---- pass 2: re-stream hebb (L3 hits), write hebb_new ----------------
    for (int t = 0; t < 8; t += 2) {
        const int i = r0 + t;
        const float4* xp = hb4 + (size_t)i * (HS_ / 4);
        const float4 x0 = xp[lane],       x1 = xp[lane + 64];
        const float4 y0 = xp[128 + lane], y1 = xp[128 + lane + 64];
        const float scA = da_b * s_hrow[lr0 + t];
        const float scB = da_b * s_hrow[lr0 + t + 1];

        float4 o0, o1, p0, p1;
        o0.x = clip1(fmaf(scA, h0.x, x0.x));
        o0.y = clip1(fmaf(scA, h0.y, x0.y));
        o0.z = clip1(fmaf(scA, h0.z, x0.z));
        o0.w = clip1(fmaf(scA, h0.w, x0.w));
        o1.x = clip1(fmaf(scA, h1.x, x1.x));
        o1.y = clip1(fmaf(scA, h1.y, x1.y));
        o1.z = clip1(fmaf(scA, h1.z, x1.z));
        o1.w = clip1(fmaf(scA, h1.w, x1.w));
        p0.x = clip1(fmaf(scB, h0.x, y0.x));
        p0.y = clip1(fmaf(scB, h0.y, y0.y));
        p0.z = clip1(fmaf(scB, h0.z, y0.z));
        p0.w = clip1(fmaf(scB, h0.w, y0.w));
        p1.x = clip1(fmaf(scB, h1.x, y1.x));
        p1.y = clip1(fmaf(scB, h1.y, y1.y));
        p1.z = clip1(fmaf(scB, h1.z, y1.z));
        p1.w = clip1(fmaf(scB, h1.w, y1.w));

        float4* dp = (float4*)hebb_new + ((size_t)b * HS_ + i) * (HS_ / 4);
        dp[lane]            = o0;
        dp[lane + 64]       = o1;
        dp[128 + lane]      = p0;
        dp[128 + lane + 64] = p1;
    }

    // ---- head: activout (this block does its 32 of the 256 outputs) ------
    if (tid < 128)
        ((float4*)s_h)[tid] = ((const float4*)(hactiv + (size_t)b * HS_))[tid];
    __syncthreads();

    {
        // 32 outputs x 16 dot-segments (32 floats = 8 float4 each)
        const int ol = tid & 31;
        const int sg = tid >> 5;            // 0..15
        const int o  = s * 32 + ol;
        const float4* wp  = (const float4*)(h2o_w + (size_t)o * HS_);
        const float4* hp4 = (const float4*)s_h;
        float acc = 0.f;
        #pragma unroll
        for (int c2 = 0; c2 < 8; ++c2) {
            const float4 wv = wp[sg * 8 + c2];
            const float4 hv = hp4[sg * 8 + c2];
            acc += wv.x * hv.x + wv.y * hv.y + wv.z * hv.z + wv.w * hv.w;
        }
        s_part[sg * 32 + ol] = acc;
    }
    __syncthreads();
    if (tid < 32) {
        const int o = s * 32 + tid;
        float acc = h2o_b[o];
        #pragma unroll
        for (int k = 0; k < 16; ++k)
            acc += s_part[k * 32 + tid];
        activout[(size_t)b * OUT_ + o] = acc;
    }
}

// ---------------------------------------------------------------------------
// Fallback path (original verified 3-kernel version) — used if the workspace
// is too small for the gate state, or if the occupancy query reports the
// fused kernel cannot keep 4 blocks/CU resident (spin-gate safety).
// ---------------------------------------------------------------------------
__global__ __launch_bounds__(256) void k1_hactiv(
    const float* __restrict__ inputs, const float* __restrict__ hidden,
    const float* __restrict__ hebb, const float* __restrict__ i2h_w,
    const float* __restrict__ i2h_b, const float* __restrict__ w,
    const float* __restrict__ alpha, float* __restrict__ hactiv)
{
    const int b     = blockIdx.x & (B_ - 1);
    const int chunk = blockIdx.x >> 7;
    const int tid   = threadIdx.x;
    const int wave  = tid >> 6;
    const int lane  = tid & 63;

    const float4* hid4 = (const float4*)(hidden + (size_t)b * HS_);
    const float4  h0   = hid4[lane];
    const float4  h1   = hid4[lane + 64];
    const float4  in4  = ((const float4*)(inputs + (size_t)b * IN_))[lane];

    const int i0 = chunk * 64 + wave * 16;

    for (int r = 0; r < 16; ++r) {
        const int i = i0 + r;
        const float4* hb = (const float4*)(hebb + ((size_t)b * HS_ + i) * HS_);
        const float4* wr = (const float4*)(w     + (size_t)i * HS_);
        const float4* ar = (const float4*)(alpha + (size_t)i * HS_);

        const float4 hb0 = hb[lane];
        const float4 hb1 = hb[lane + 64];
        const float4 wv0 = wr[lane];
        const float4 wv1 = wr[lane + 64];
        const float4 av0 = ar[lane];
        const float4 av1 = ar[lane + 64];
        const float4 iw  = ((const float4*)(i2h_w + (size_t)i * IN_))[lane];

        float acc;
        acc  = (wv0.x + av0.x * hb0.x) * h0.x;
        acc += (wv0.y + av0.y * hb0.y) * h0.y;
        acc += (wv0.z + av0.z * hb0.z) * h0.z;
        acc += (wv0.w + av0.w * hb0.w) * h0.w;
        acc += (wv1.x + av1.x * hb1.x) * h1.x;
        acc += (wv1.y + av1.y * hb1.y) * h1.y;
        acc += (wv1.z + av1.z * hb1.z) * h1.z;
        acc += (wv1.w + av1.w * hb1.w) * h1.w;
        acc += iw.x * in4.x + iw.y * in4.y + iw.z * in4.z + iw.w * in4.w;

        #pragma unroll
        for (int off = 32; off > 0; off >>= 1)
            acc += __shfl_down(acc, off, 64);

        if (lane == 0)
            hactiv[(size_t)b * HS_ + i] = tanhf(acc + i2h_b[i]);
    }
}

__global__ __launch_bounds__(256) void k2_heads(
    const float* __restrict__ hactiv, const float* __restrict__ h2o_w,
    const float* __restrict__ h2o_b, const float* __restrict__ h2v_w,
    const float* __restrict__ h2v_b, const float* __restrict__ h2da_w,
    const float* __restrict__ h2da_b, float* __restrict__ activout,
    float* __restrict__ valueout, float* __restrict__ da)
{
    const int b   = blockIdx.x;
    const int tid = threadIdx.x;

    __shared__ float s_h[HS_];
    __shared__ float red_v[256];
    __shared__ float red_d[256];

    for (int t = tid; t < HS_; t += 256)
        s_h[t] = hactiv[(size_t)b * HS_ + t];
    __syncthreads();

    const float4* wr  = (const float4*)(h2o_w + (size_t)tid * HS_);
    const float4* sh4 = (const float4*)s_h;
    float acc = 0.f;
    #pragma unroll 4
    for (int q = 0; q < HS_ / 4; ++q) {
        const float4 wv = wr[q];
        const float4 hv = sh4[q];
        acc += wv.x * hv.x + wv.y * hv.y + wv.z * hv.z + wv.w * hv.w;
    }
    activout[(size_t)b * OUT_ + tid] = acc + h2o_b[tid];

    float pv = 0.f, pd = 0.f;
    for (int t = tid; t < HS_; t += 256) {
        const float hv = s_h[t];
        pv += hv * h2v_w[t];
        pd += hv * h2da_w[t];
    }
    red_v[tid] = pv;
    red_d[tid] = pd;
    __syncthreads();
    for (int s2 = 128; s2 > 0; s2 >>= 1) {
        if (tid < s2) {
            red_v[tid] += red_v[tid + s2];
            red_d[tid] += red_d[tid + s2];
        }
        __syncthreads();
    }
    if (tid == 0) {
        valueout[b] = red_v[0] + h2v_b[0];
        da[b]       = tanhf(red_d[0] + h2da_b[0]);
    }
}

__global__ __launch_bounds__(256) void k3_hebb(
    const float* __restrict__ hebb, const float* __restrict__ hidden,
    const float* __restrict__ hactiv, const float* __restrict__ da,
    float* __restrict__ hebb_new)
{
    const int tid = threadIdx.x;
    const size_t base = (size_t)blockIdx.x * 1024;

    #pragma unroll
    for (int k = 0; k < 4; ++k) {
        const size_t idx = base + (size_t)k * 256 + tid;
        const int j4  = (int)(idx & 127);
        const int row = (int)(idx >> 7);
        const int i   = row & (HS_ - 1);
        const int b   = row >> 9;

        const float scale = da[b] * hactiv[(size_t)b * HS_ + i];
        const float4 hv = ((const float4*)hebb)[idx];
        const float4 hd = ((const float4*)hidden)[(size_t)b * (HS_ / 4) + j4];

        float4 r;
        r.x = fminf(fmaxf(fmaf(scale, hd.x, hv.x), -1.f), 1.f);
        r.y = fminf(fmaxf(fmaf(scale, hd.y, hv.y), -1.f), 1.f);
        r.z = fminf(fmaxf(fmaf(scale, hd.z, hv.z), -1.f), 1.f);
        r.w = fminf(fmaxf(fmaf(scale, hd.w, hv.w), -1.f), 1.f);
        ((float4*)hebb_new)[idx] = r;
    }
}

// ---------------------------------------------------------------------------
extern "C" void kernel_launch(void* const* d_in, const int* in_sizes, int n_in,
                              void* d_out, int out_size, void* d_ws, size_t ws_size,
                              hipStream_t stream)
{
    const float* inputs = (const float*)d_in[0];
    const float* hidden = (const float*)d_in[1];
    const float* hebb   = (const float*)d_in[2];
    const float* i2h_w  = (const float*)d_in[3];
    const float* i2h_b  = (const float*)d_in[4];
    const float* w      = (const float*)d_in[5];
    const float* alpha  = (const float*)d_in[6];
    const float* h2o_w  = (const float*)d_in[7];
    const float* h2o_b  = (const float*)d_in[8];
    const float* h2v_w  = (const float*)d_in[9];
    const float* h2v_b  = (const float*)d_in[10];
    const float* h2da_w = (const float*)d_in[11];
    const float* h2da_b = (const float*)d_in[12];

    float* out = (float*)d_out;
    // Output layout (flat, return order): activout | valueout | hactiv | hebb_new
    float* activout = out;                              // 128*256   = 32768
    float* valueout = out + 32768;                      // 128
    float* hactiv   = out + 32768 + 128;                // 128*512   = 65536
    float* hebb_new = out + 32768 + 128 + 65536;        // 128*512*512

    const size_t gate_bytes = (size_t)(3 * B_) * sizeof(float);   // 1.5 KB

    int maxb = 0;
    hipError_t oe = hipOccupancyMaxActiveBlocksPerMultiprocessor(
        &maxb, fused_stream, NTHR_, 0);

    if (ws_size >= gate_bytes && oe == hipSuccess && maxb >= 4) {
        float* ws_pd  = (float*)d_ws;                   // [128]
        float* ws_pv  = ws_pd + B_;                     // [128]
        int*   ws_cnt = (int*)(ws_pv + B_);             // [128]

        // Zero the gate state each launch (graph-capturable stream op).
        hipMemsetAsync(d_ws, 0, gate_bytes, stream);

        fused_stream<<<dim3(NBLK_), dim3(NTHR_), 0, stream>>>(
            inputs, hidden, hebb, i2h_w, i2h_b, w, alpha,
            h2o_w, h2o_b, h2v_w, h2v_b, h2da_w, h2da_b,
            activout, valueout, hactiv, hebb_new,
            ws_pd, ws_pv, ws_cnt);
    } else {
        float* da = (float*)d_ws;                       // [128] scratch
        k1_hactiv<<<dim3(1024), dim3(256), 0, stream>>>(
            inputs, hidden, hebb, i2h_w, i2h_b, w, alpha, hactiv);
        k2_heads<<<dim3(B_), dim3(256), 0, stream>>>(
            hactiv, h2o_w, h2o_b, h2v_w, h2v_b, h2da_w, h2da_b,
            activout, valueout, da);
        k3_hebb<<<dim3(8192), dim3(256), 0, stream>>>(
            hebb, hidden, hactiv, da, hebb_new);
    }
}

// Round 6
// 285.474 us; speedup vs baseline: 2.7503x; 1.0497x over previous
//
#include <hip/hip_runtime.h>
#include <cstddef>
#include <cstdint>

// Problem constants (all powers of two).
#define B_    128
#define IN_   256
#define OUT_  256
#define HS_   512

#define NTHR_  512
#define NBLK_  1024   // 8 sibling blocks per sample, 64 rows each

__device__ __forceinline__ float clip1(float x) {
    return fminf(fmaxf(x, -1.f), 1.f);
}

typedef float f32x4 __attribute__((ext_vector_type(4)));
__device__ __forceinline__ void nt_store4(float4* p, float4 v) {
    // nontemporal: hebb_new is write-once, never re-read -> don't pollute
    // L2/L3 (which we want to keep holding hebb for the pass-2 re-read).
    __builtin_nontemporal_store(*(f32x4*)&v, (f32x4*)p);
}

// ---------------------------------------------------------------------------
// Pass 1: hactiv + da/value partials. 1024 blocks x 512 threads =
// 4 blocks/CU = 32 waves/CU (round-5 verified: 64 VGPR, ~70% occupancy).
// Streams hebb once from HBM (loads populate L3 for pass 2's re-read).
// Partials are PLAIN stores to per-(sample,sibling) slots -- the kernel
// boundary provides the sync + visibility, so no memset/atomics/spin.
// ---------------------------------------------------------------------------
__global__ __launch_bounds__(NTHR_, 4) void k_pass1(
    const float* __restrict__ inputs,   // [B, IN]
    const float* __restrict__ hidden,   // [B, HS]
    const float* __restrict__ hebb,     // [B, HS, HS]
    const float* __restrict__ i2h_w,    // [HS, IN]
    const float* __restrict__ i2h_b,    // [HS]
    const float* __restrict__ w,        // [HS, HS]
    const float* __restrict__ alpha,    // [HS, HS]
    const float* __restrict__ h2v_w,    // [HS]
    const float* __restrict__ h2da_w,   // [HS]
    float* __restrict__ hactiv,         // [B, HS]
    float* __restrict__ ws_pd,          // [B*8] da partials (plain stores)
    float* __restrict__ ws_pv)          // [B*8] value partials
{
    const int blk  = blockIdx.x;
    const int b    = blk >> 3;          // sample
    const int s    = blk & 7;           // sibling 0..7
    const int tid  = threadIdx.x;
    const int wave = tid >> 6;          // 0..7
    const int lane = tid & 63;
    const int r0   = s * 64 + wave * 8; // first row of this wave

    __shared__ float s_pd[8], s_pv[8];

    // Lane-fixed per-sample operands.
    const float4* hid4 = (const float4*)(hidden + (size_t)b * HS_);
    const float4 h0  = hid4[lane];
    const float4 h1  = hid4[lane + 64];
    const float4 in4 = ((const float4*)(inputs + (size_t)b * IN_))[lane];

    const float4* hb4 = (const float4*)hebb + ((size_t)b * HS_) * (HS_ / 4);
    const float4* w4  = (const float4*)w;
    const float4* a4  = (const float4*)alpha;
    const float4* iw4 = (const float4*)i2h_w;

    float pd = 0.f, pv = 0.f;
    for (int t = 0; t < 8; t += 2) {
        const int i = r0 + t;
        const float4* hpA = hb4 + (size_t)i * (HS_ / 4);
        const float4* hpB = hpA + (HS_ / 4);
        const float4* wpA = w4  + (size_t)i * (HS_ / 4);
        const float4* apA = a4  + (size_t)i * (HS_ / 4);
        const float4* ipA = iw4 + (size_t)i * (IN_ / 4);

        // 14 independent float4 loads (kept in flight)
        const float4 xA0 = hpA[lane],            xA1 = hpA[lane + 64];
        const float4 xB0 = hpB[lane],            xB1 = hpB[lane + 64];
        const float4 wA0 = wpA[lane],            wA1 = wpA[lane + 64];
        const float4 wB0 = wpA[128 + lane],      wB1 = wpA[128 + lane + 64];
        const float4 aA0 = apA[lane],            aA1 = apA[lane + 64];
        const float4 aB0 = apA[128 + lane],      aB1 = apA[128 + lane + 64];
        const float4 iA  = ipA[lane];
        const float4 iB  = ipA[64 + lane];

        float a, c;
        a  = (wA0.x + aA0.x * xA0.x) * h0.x;
        a += (wA0.y + aA0.y * xA0.y) * h0.y;
        a += (wA0.z + aA0.z * xA0.z) * h0.z;
        a += (wA0.w + aA0.w * xA0.w) * h0.w;
        a += (wA1.x + aA1.x * xA1.x) * h1.x;
        a += (wA1.y + aA1.y * xA1.y) * h1.y;
        a += (wA1.z + aA1.z * xA1.z) * h1.z;
        a += (wA1.w + aA1.w * xA1.w) * h1.w;
        a += iA.x * in4.x + iA.y * in4.y + iA.z * in4.z + iA.w * in4.w;

        c  = (wB0.x + aB0.x * xB0.x) * h0.x;
        c += (wB0.y + aB0.y * xB0.y) * h0.y;
        c += (wB0.z + aB0.z * xB0.z) * h0.z;
        c += (wB0.w + aB0.w * xB0.w) * h0.w;
        c += (wB1.x + aB1.x * xB1.x) * h1.x;
        c += (wB1.y + aB1.y * xB1.y) * h1.y;
        c += (wB1.z + aB1.z * xB1.z) * h1.z;
        c += (wB1.w + aB1.w * xB1.w) * h1.w;
        c += iB.x * in4.x + iB.y * in4.y + iB.z * in4.z + iB.w * in4.w;

        // two independent 6-step butterflies (chains overlap)
        #pragma unroll
        for (int off = 1; off < 64; off <<= 1) {
            a += __shfl_xor(a, off, 64);
            c += __shfl_xor(c, off, 64);
        }

        const float hA = tanhf(a + i2h_b[i]);
        const float hB = tanhf(c + i2h_b[i + 1]);
        if (lane == 0) {
            float2* hp = (float2*)(hactiv + (size_t)b * HS_ + i);
            *hp = make_float2(hA, hB);
            pd += hA * h2da_w[i] + hB * h2da_w[i + 1];
            pv += hA * h2v_w[i]  + hB * h2v_w[i + 1];
        }
    }

    if (lane == 0) { s_pd[wave] = pd; s_pv[wave] = pv; }
    __syncthreads();
    if (tid == 0) {
        float sd = 0.f, sv = 0.f;
        #pragma unroll
        for (int k = 0; k < 8; ++k) { sd += s_pd[k]; sv += s_pv[k]; }
        ws_pd[b * 8 + s] = sd;      // plain store; kernel boundary = sync
        ws_pv[b * 8 + s] = sv;
    }
}

// ---------------------------------------------------------------------------
// Pass 2: finalize da (partials complete at kernel boundary), hebb update
// (hebb re-read is L3-resident from pass 1; hebb_new written nontemporal),
// valueout, and the activout head. Same geometry as pass 1.
// ---------------------------------------------------------------------------
__global__ __launch_bounds__(NTHR_, 4) void k_pass2(
    const float* __restrict__ hidden,   // [B, HS]
    const float* __restrict__ hebb,     // [B, HS, HS]
    const float* __restrict__ h2o_w,    // [OUT, HS]
    const float* __restrict__ h2o_b,    // [OUT]
    const float* __restrict__ h2v_b,    // [1]
    const float* __restrict__ h2da_b,   // [1]
    const float* __restrict__ hactiv,   // [B, HS]
    float* __restrict__ activout,       // [B, OUT]
    float* __restrict__ valueout,       // [B]
    float* __restrict__ hebb_new,       // [B, HS, HS]
    const float* __restrict__ ws_pd,    // [B*8]
    const float* __restrict__ ws_pv)    // [B*8]
{
    const int blk  = blockIdx.x;
    const int b    = blk >> 3;
    const int s    = blk & 7;
    const int tid  = threadIdx.x;
    const int wave = tid >> 6;
    const int lane = tid & 63;
    const int r0   = s * 64 + wave * 8;

    __shared__ float s_h[HS_];          // full hactiv[b]
    __shared__ float s_part[512];
    __shared__ float s_bc[1];           // da broadcast

    if (tid < 128)
        ((float4*)s_h)[tid] = ((const float4*)(hactiv + (size_t)b * HS_))[tid];
    if (tid == 0) {
        float sd = 0.f, sv = 0.f;
        #pragma unroll
        for (int k = 0; k < 8; ++k) {
            sd += ws_pd[b * 8 + k];
            sv += ws_pv[b * 8 + k];
        }
        s_bc[0] = tanhf(sd + h2da_b[0]);
        if (s == 0)
            valueout[b] = sv + h2v_b[0];
    }
    __syncthreads();
    const float da_b = s_bc[0];

    // Lane-fixed per-sample operand.
    const float4* hid4 = (const float4*)(hidden + (size_t)b * HS_);
    const float4 h0 = hid4[lane];
    const float4 h1 = hid4[lane + 64];

    const float4* hb4 = (const float4*)hebb + ((size_t)b * HS_) * (HS_ / 4);

    for (int t = 0; t < 8; t += 2) {
        const int i = r0 + t;
        const float4* xp = hb4 + (size_t)i * (HS_ / 4);
        const float4 x0 = xp[lane],       x1 = xp[lane + 64];
        const float4 y0 = xp[128 + lane], y1 = xp[128 + lane + 64];
        const float scA = da_b * s_h[i];
        const float scB = da_b * s_h[i + 1];

        float4 o0, o1, p0, p1;
        o0.x = clip1(fmaf(scA, h0.x, x0.x));
        o0.y = clip1(fmaf(scA, h0.y, x0.y));
        o0.z = clip1(fmaf(scA, h0.z, x0.z));
        o0.w = clip1(fmaf(scA, h0.w, x0.w));
        o1.x = clip1(fmaf(scA, h1.x, x1.x));
        o1.y = clip1(fmaf(scA, h1.y, x1.y));
        o1.z = clip1(fmaf(scA, h1.z, x1.z));
        o1.w = clip1(fmaf(scA, h1.w, x1.w));
        p0.x = clip1(fmaf(scB, h0.x, y0.x));
        p0.y = clip1(fmaf(scB, h0.y, y0.y));
        p0.z = clip1(fmaf(scB, h0.z, y0.z));
        p0.w = clip1(fmaf(scB, h0.w, y0.w));
        p1.x = clip1(fmaf(scB, h1.x, y1.x));
        p1.y = clip1(fmaf(scB, h1.y, y1.y));
        p1.z = clip1(fmaf(scB, h1.z, y1.z));
        p1.w = clip1(fmaf(scB, h1.w, y1.w));

        float4* dp = (float4*)hebb_new + ((size_t)b * HS_ + i) * (HS_ / 4);
        nt_store4(dp + lane,            o0);
        nt_store4(dp + lane + 64,       o1);
        nt_store4(dp + 128 + lane,      p0);
        nt_store4(dp + 128 + lane + 64, p1);
    }

    // ---- head: this block computes its 32 of the 256 outputs -------------
    {
        const int ol = tid & 31;
        const int sg = tid >> 5;            // 0..15 dot-segment
        const int o  = s * 32 + ol;
        const float4* wp  = (const float4*)(h2o_w + (size_t)o * HS_);
        const float4* hp4 = (const float4*)s_h;
        float acc = 0.f;
        #pragma unroll
        for (int c2 = 0; c2 < 8; ++c2) {
            const float4 wv = wp[sg * 8 + c2];
            const float4 hv = hp4[sg * 8 + c2];
            acc += wv.x * hv.x + wv.y * hv.y + wv.z * hv.z + wv.w * hv.w;
        }
        s_part[sg * 32 + ol] = acc;
    }
    __syncthreads();
    if (tid < 32) {
        const int o = s * 32 + tid;
        float acc = h2o_b[o];
        #pragma unroll
        for (int k = 0; k < 16; ++k)
            acc += s_part[k * 32 + tid];
        activout[(size_t)b * OUT_ + o] = acc;
    }
}

// ---------------------------------------------------------------------------
// Fallback path (original verified 3-kernel version) — used only if the
// workspace is too small for the 8 KB of partials.
// ---------------------------------------------------------------------------
__global__ __launch_bounds__(256) void k1_hactiv(
    const float* __restrict__ inputs, const float* __restrict__ hidden,
    const float* __restrict__ hebb, const float* __restrict__ i2h_w,
    const float* __restrict__ i2h_b, const float* __restrict__ w,
    const float* __restrict__ alpha, float* __restrict__ hactiv)
{
    const int b     = blockIdx.x & (B_ - 1);
    const int chunk = blockIdx.x >> 7;
    const int tid   = threadIdx.x;
    const int wave  = tid >> 6;
    const int lane  = tid & 63;

    const float4* hid4 = (const float4*)(hidden + (size_t)b * HS_);
    const float4  h0   = hid4[lane];
    const float4  h1   = hid4[lane + 64];
    const float4  in4  = ((const float4*)(inputs + (size_t)b * IN_))[lane];

    const int i0 = chunk * 64 + wave * 16;

    for (int r = 0; r < 16; ++r) {
        const int i = i0 + r;
        const float4* hb = (const float4*)(hebb + ((size_t)b * HS_ + i) * HS_);
        const float4* wr = (const float4*)(w     + (size_t)i * HS_);
        const float4* ar = (const float4*)(alpha + (size_t)i * HS_);

        const float4 hb0 = hb[lane];
        const float4 hb1 = hb[lane + 64];
        const float4 wv0 = wr[lane];
        const float4 wv1 = wr[lane + 64];
        const float4 av0 = ar[lane];
        const float4 av1 = ar[lane + 64];
        const float4 iw  = ((const float4*)(i2h_w + (size_t)i * IN_))[lane];

        float acc;
        acc  = (wv0.x + av0.x * hb0.x) * h0.x;
        acc += (wv0.y + av0.y * hb0.y) * h0.y;
        acc += (wv0.z + av0.z * hb0.z) * h0.z;
        acc += (wv0.w + av0.w * hb0.w) * h0.w;
        acc += (wv1.x + av1.x * hb1.x) * h1.x;
        acc += (wv1.y + av1.y * hb1.y) * h1.y;
        acc += (wv1.z + av1.z * hb1.z) * h1.z;
        acc += (wv1.w + av1.w * hb1.w) * h1.w;
        acc += iw.x * in4.x + iw.y * in4.y + iw.z * in4.z + iw.w * in4.w;

        #pragma unroll
        for (int off = 32; off > 0; off >>= 1)
            acc += __shfl_down(acc, off, 64);

        if (lane == 0)
            hactiv[(size_t)b * HS_ + i] = tanhf(acc + i2h_b[i]);
    }
}

__global__ __launch_bounds__(256) void k2_heads(
    const float* __restrict__ hactiv, const float* __restrict__ h2o_w,
    const float* __restrict__ h2o_b, const float* __restrict__ h2v_w,
    const float* __restrict__ h2v_b, const float* __restrict__ h2da_w,
    const float* __restrict__ h2da_b, float* __restrict__ activout,
    float* __restrict__ valueout, float* __restrict__ da)
{
    const int b   = blockIdx.x;
    const int tid = threadIdx.x;

    __shared__ float s_h[HS_];
    __shared__ float red_v[256];
    __shared__ float red_d[256];

    for (int t = tid; t < HS_; t += 256)
        s_h[t] = hactiv[(size_t)b * HS_ + t];
    __syncthreads();

    const float4* wr  = (const float4*)(h2o_w + (size_t)tid * HS_);
    const float4* sh4 = (const float4*)s_h;
    float acc = 0.f;
    #pragma unroll 4
    for (int q = 0; q < HS_ / 4; ++q) {
        const float4 wv = wr[q];
        const float4 hv = sh4[q];
        acc += wv.x * hv.x + wv.y * hv.y + wv.z * hv.z + wv.w * hv.w;
    }
    activout[(size_t)b * OUT_ + tid] = acc + h2o_b[tid];

    float pv = 0.f, pd = 0.f;
    for (int t = tid; t < HS_; t += 256) {
        const float hv = s_h[t];
        pv += hv * h2v_w[t];
        pd += hv * h2da_w[t];
    }
    red_v[tid] = pv;
    red_d[tid] = pd;
    __syncthreads();
    for (int s2 = 128; s2 > 0; s2 >>= 1) {
        if (tid < s2) {
            red_v[tid] += red_v[tid + s2];
            red_d[tid] += red_d[tid + s2];
        }
        __syncthreads();
    }
    if (tid == 0) {
        valueout[b] = red_v[0] + h2v_b[0];
        da[b]       = tanhf(red_d[0] + h2da_b[0]);
    }
}

__global__ __launch_bounds__(256) void k3_hebb(
    const float* __restrict__ hebb, const float* __restrict__ hidden,
    const float* __restrict__ hactiv, const float* __restrict__ da,
    float* __restrict__ hebb_new)
{
    const int tid = threadIdx.x;
    const size_t base = (size_t)blockIdx.x * 1024;

    #pragma unroll
    for (int k = 0; k < 4; ++k) {
        const size_t idx = base + (size_t)k * 256 + tid;
        const int j4  = (int)(idx & 127);
        const int row = (int)(idx >> 7);
        const int i   = row & (HS_ - 1);
        const int b   = row >> 9;

        const float scale = da[b] * hactiv[(size_t)b * HS_ + i];
        const float4 hv = ((const float4*)hebb)[idx];
        const float4 hd = ((const float4*)hidden)[(size_t)b * (HS_ / 4) + j4];

        float4 r;
        r.x = fminf(fmaxf(fmaf(scale, hd.x, hv.x), -1.f), 1.f);
        r.y = fminf(fmaxf(fmaf(scale, hd.y, hv.y), -1.f), 1.f);
        r.z = fminf(fmaxf(fmaf(scale, hd.z, hv.z), -1.f), 1.f);
        r.w = fminf(fmaxf(fmaf(scale, hd.w, hv.w), -1.f), 1.f);
        ((float4*)hebb_new)[idx] = r;
    }
}

// ---------------------------------------------------------------------------
extern "C" void kernel_launch(void* const* d_in, const int* in_sizes, int n_in,
                              void* d_out, int out_size, void* d_ws, size_t ws_size,
                              hipStream_t stream)
{
    const float* inputs = (const float*)d_in[0];
    const float* hidden = (const float*)d_in[1];
    const float* hebb   = (const float*)d_in[2];
    const float* i2h_w  = (const float*)d_in[3];
    const float* i2h_b  = (const float*)d_in[4];
    const float* w      = (const float*)d_in[5];
    const float* alpha  = (const float*)d_in[6];
    const float* h2o_w  = (const float*)d_in[7];
    const float* h2o_b  = (const float*)d_in[8];
    const float* h2v_w  = (const float*)d_in[9];
    const float* h2v_b  = (const float*)d_in[10];
    const float* h2da_w = (const float*)d_in[11];
    const float* h2da_b = (const float*)d_in[12];

    float* out = (float*)d_out;
    // Output layout (flat, return order): activout | valueout | hactiv | hebb_new
    float* activout = out;                              // 128*256   = 32768
    float* valueout = out + 32768;                      // 128
    float* hactiv   = out + 32768 + 128;                // 128*512   = 65536
    float* hebb_new = out + 32768 + 128 + 65536;        // 128*512*512

    const size_t part_bytes = (size_t)(2 * B_ * 8) * sizeof(float);   // 8 KB

    if (ws_size >= part_bytes) {
        float* ws_pd = (float*)d_ws;                    // [128*8]
        float* ws_pv = ws_pd + B_ * 8;                  // [128*8]

        k_pass1<<<dim3(NBLK_), dim3(NTHR_), 0, stream>>>(
            inputs, hidden, hebb, i2h_w, i2h_b, w, alpha,
            h2v_w, h2da_w, hactiv, ws_pd, ws_pv);

        k_pass2<<<dim3(NBLK_), dim3(NTHR_), 0, stream>>>(
            hidden, hebb, h2o_w, h2o_b, h2v_b, h2da_b,
            hactiv, activout, valueout, hebb_new, ws_pd, ws_pv);
    } else {
        float* da = (float*)d_ws;                       // [128] scratch
        k1_hactiv<<<dim3(1024), dim3(256), 0, stream>>>(
            inputs, hidden, hebb, i2h_w, i2h_b, w, alpha, hactiv);
        k2_heads<<<dim3(B_), dim3(256), 0, stream>>>(
            hactiv, h2o_w, h2o_b, h2v_w, h2v_b, h2da_w, h2da_b,
            activout, valueout, da);
        k3_hebb<<<dim3(8192), dim3(256), 0, stream>>>(
            hebb, hidden, hactiv, da, hebb_new);
    }
}